// Round 12
// baseline (154.906 us; speedup 1.0000x reference)
//
#include <hip/hip_runtime.h>
#include <hip/hip_bf16.h>

#define NSEQ 2048
#define BATCH 4

typedef __attribute__((ext_vector_type(8))) short bf16x8;
typedef __attribute__((ext_vector_type(4))) short s16x4;
typedef __attribute__((ext_vector_type(4))) float f32x4;

static __device__ inline ushort2 pk_bf2(float a, float b) {
    __hip_bfloat162 h = __float22bfloat162_rn(make_float2(a, b));
    return *reinterpret_cast<ushort2*>(&h);
}
static __device__ inline ushort bf1(float a) { return pk_bf2(a, a).x; }
static __device__ inline ushort4 pk_bf4u(float a, float b, float c, float d) {
    ushort2 lo = pk_bf2(a, b), hi = pk_bf2(c, d);
    return make_ushort4(lo.x, lo.y, hi.x, hi.y);
}
static __device__ inline s16x4 pk_bf4(float a, float b, float c, float d) {
    __hip_bfloat162 lo = __float22bfloat162_rn(make_float2(a, b));
    __hip_bfloat162 hi = __float22bfloat162_rn(make_float2(c, d));
    uint2 u = make_uint2(*reinterpret_cast<uint*>(&lo), *reinterpret_cast<uint*>(&hi));
    return __builtin_bit_cast(s16x4, u);
}

static __device__ inline float fexp2(float x) {
#if __has_builtin(__builtin_amdgcn_exp2f)
    return __builtin_amdgcn_exp2f(x);
#else
    return __expf(x * 0.69314718056f);
#endif
}

// async 16B/lane global->LDS; lds base wave-uniform (HW writes base + lane*16)
static __device__ inline void gload_lds16(const ushort* g, ushort* l) {
    __builtin_amdgcn_global_load_lds(
        (const __attribute__((address_space(1))) unsigned int*)g,
        (__attribute__((address_space(3))) unsigned int*)l,
        16, 0, 0);
}

// ---- cvt: blocks 0..511 transpose x -> xb [b][n][256] bf16; 512..1023 convert w_qkv/w_out ----
__global__ __launch_bounds__(256)
void cvt_all(const float* __restrict__ x, const float* __restrict__ wq,
             const float* __restrict__ wo, ushort* __restrict__ xb,
             ushort* __restrict__ wqb, ushort* __restrict__ wob)
{
    const int tid = threadIdx.x;
    const int id  = blockIdx.x;
    if (id < 512) {
        const int b  = id >> 7;
        const int ct = (id & 127) >> 5;
        const int nt = id & 31;
        const int c0 = ct * 64, n0 = nt * 64;
        __shared__ __align__(16) ushort T[64][72];
        #pragma unroll
        for (int it = 0; it < 4; ++it) {
            const int c  = it * 16 + (tid >> 4);
            const int n4 = (tid & 15) * 4;
            float4 v = *(const float4*)(x + ((size_t)b * 256 + c0 + c) * NSEQ + n0 + n4);
            T[n4 + 0][c] = bf1(v.x); T[n4 + 1][c] = bf1(v.y);
            T[n4 + 2][c] = bf1(v.z); T[n4 + 3][c] = bf1(v.w);
        }
        __syncthreads();
        const int n  = tid >> 2;
        const int cg = (tid & 3) * 16;
        ushort* dst = xb + ((size_t)b * NSEQ + n0 + n) * 256 + c0 + cg;
        *(uint4*)dst       = *(const uint4*)&T[n][cg];
        *(uint4*)(dst + 8) = *(const uint4*)&T[n][cg + 8];
    } else {
        const int f = (id - 512) * 256 + tid;
        const float* s; ushort* d; int off;
        if (f < 98304) { s = wq; d = wqb; off = f; }
        else           { s = wo; d = wob; off = f - 98304; }
        float4 v = ((const float4*)s)[off];
        ((ushort4*)d)[off] = pk_bf4u(v.x, v.y, v.z, v.w);
    }
}

// ---- GEMM1 (R9 version): qkv = w_qkv @ x. A=wqb[o][k], B=xb[b][n][k]. 128x128, BK=64, K=256. ----
__global__ __launch_bounds__(256)
void gemm_qkv(const ushort* __restrict__ A, const ushort* __restrict__ X,
              ushort* __restrict__ Qt, ushort* __restrict__ Kt, ushort* __restrict__ vb)
{
    const int tid = threadIdx.x;
    const int w = tid >> 6, l15 = tid & 15, quad = (tid & 63) >> 4;
    const int lr8 = (tid & 63) >> 3, lc8 = tid & 7;
    const int sw  = l15 & 7;
    const int n0 = blockIdx.x * 128, o0 = blockIdx.y * 128, b = blockIdx.z;

    __shared__ __align__(16) ushort As[128 * 64];
    __shared__ __align__(16) ushort Bs[128 * 64];

    f32x4 acc[2][8];
    const f32x4 z4 = {0.f, 0.f, 0.f, 0.f};
    #pragma unroll
    for (int mt = 0; mt < 2; ++mt)
        #pragma unroll
        for (int nt = 0; nt < 8; ++nt) acc[mt][nt] = z4;

    for (int k0 = 0; k0 < 256; k0 += 64) {
        __syncthreads();
        #pragma unroll
        for (int t = 0; t < 4; ++t) {
            const int rb = w * 32 + t * 8;
            gload_lds16(A + (size_t)(o0 + rb + lr8) * 256 + k0 + (lc8 ^ lr8) * 8,
                        As + rb * 64);
            gload_lds16(X + ((size_t)b * NSEQ + n0 + rb + lr8) * 256 + k0 + (lc8 ^ lr8) * 8,
                        Bs + rb * 64);
        }
        __syncthreads();
        #pragma unroll
        for (int kk = 0; kk < 2; ++kk) {
            bf16x8 a0 = *(const bf16x8*)&As[(w * 32 + l15) * 64 + ((kk * 4 + quad) ^ sw) * 8];
            bf16x8 a1 = *(const bf16x8*)&As[(w * 32 + 16 + l15) * 64 + ((kk * 4 + quad) ^ sw) * 8];
            #pragma unroll
            for (int nt = 0; nt < 8; ++nt) {
                bf16x8 bb = *(const bf16x8*)&Bs[(nt * 16 + l15) * 64 + ((kk * 4 + quad) ^ sw) * 8];
                acc[0][nt] = __builtin_amdgcn_mfma_f32_16x16x32_bf16(a0, bb, acc[0][nt], 0, 0, 0);
                acc[1][nt] = __builtin_amdgcn_mfma_f32_16x16x32_bf16(a1, bb, acc[1][nt], 0, 0, 0);
            }
        }
    }

    if (o0 < 1024) {
        ushort* dst = (o0 < 512) ? Qt : Kt;
        const float sc = (o0 < 512) ? 0.18033688f : 1.0f;   // 0.125 * log2(e) for Q
        #pragma unroll
        for (int mt = 0; mt < 2; ++mt) {
            const int obase = (o0 & 511) + w * 32 + mt * 16;
            const int h  = obase >> 6;
            const int d0 = (obase & 63) + quad * 4;
            ushort* dh = dst + (size_t)(b * 8 + h) * NSEQ * 64;
            #pragma unroll
            for (int nt = 0; nt < 8; ++nt)
                *(ushort4*)&dh[(size_t)(n0 + nt * 16 + l15) * 64 + d0] =
                    pk_bf4u(acc[mt][nt][0] * sc, acc[mt][nt][1] * sc,
                            acc[mt][nt][2] * sc, acc[mt][nt][3] * sc);
        }
    } else {
        #pragma unroll
        for (int mt = 0; mt < 2; ++mt) {
            const int ov = o0 - 1024 + w * 32 + mt * 16 + quad * 4;
            #pragma unroll
            for (int nt = 0; nt < 8; ++nt)
                #pragma unroll
                for (int reg = 0; reg < 4; ++reg)
                    vb[((size_t)b * 512 + ov + reg) * NSEQ + n0 + nt * 16 + l15] =
                        bf1(acc[mt][nt][reg]);
        }
    }
}

// ---- flash attention v8: attn7 + V fragments via b128 broadcast reads + in-register
// half select (quads q, q^1 read the SAME 16B unit -> same-address broadcast, no
// bank conflicts; the b64 8B-granular read was the source of 4.19M conflict cycles).
__global__ __launch_bounds__(512, 4)
void attn8(const ushort* __restrict__ Qt, const ushort* __restrict__ Kt,
           const ushort* __restrict__ vb, ushort* __restrict__ attnb)
{
    const int tid  = threadIdx.x;
    const int w    = tid >> 6;          // 0..7
    const int g    = w >> 2;            // j-group
    const int ww   = w & 3;             // wave within group
    const int lane = tid & 63;
    const int l15  = lane & 15;
    const int quad = lane >> 4;
    const int lr8  = lane >> 3, lc8 = lane & 7;
    const int sw   = l15 & 7;
    const int i0   = blockIdx.x * 128;
    const int h    = blockIdx.y;
    const int b    = blockIdx.z;
    const int bh   = b * 8 + h;

    __shared__ __align__(16) ushort KVs[2][2][2][64 * 64];   // [g][buf][K/V], 64 KB

    const ushort* Qrow = Qt + (size_t)bh * NSEQ * 64;
    const ushort* Krow = Kt + (size_t)bh * NSEQ * 64;
    const ushort* Vrow = vb + ((size_t)b * 512 + h * 64) * NSEQ;

    bf16x8 qf[2][2];
    #pragma unroll
    for (int mt = 0; mt < 2; ++mt)
        #pragma unroll
        for (int kk = 0; kk < 2; ++kk)
            qf[mt][kk] = *(const bf16x8*)
                &Qrow[(size_t)(i0 + ww * 32 + mt * 16 + l15) * 64 + kk * 32 + quad * 8];

    f32x4 Oacc[4][2];
    const f32x4 z4 = {0.f, 0.f, 0.f, 0.f};
    #pragma unroll
    for (int dt = 0; dt < 4; ++dt)
        #pragma unroll
        for (int mt = 0; mt < 2; ++mt) Oacc[dt][mt] = z4;
    float lacc[2] = {0.f, 0.f};

    #pragma unroll
    for (int t = 0; t < 2; ++t) {
        const int rb = ww * 16 + t * 8;
        gload_lds16(Krow + (size_t)(g * 64 + rb + lr8) * 64 + (lc8 ^ lr8) * 8,
                    &KVs[g][0][0][rb * 64]);
        gload_lds16(Vrow + (size_t)(rb + lr8) * NSEQ + g * 64 + (lc8 ^ lr8) * 8,
                    &KVs[g][0][1][rb * 64]);
    }
    __syncthreads();

    for (int it = 0; it < 16; ++it) {
        const int p  = it & 1;
        const int jn = ((2 * (it + 1) + g) & 31) * 64;
        #pragma unroll
        for (int t = 0; t < 2; ++t) {
            const int rb = ww * 16 + t * 8;
            gload_lds16(Krow + (size_t)(jn + rb + lr8) * 64 + (lc8 ^ lr8) * 8,
                        &KVs[g][p ^ 1][0][rb * 64]);
            gload_lds16(Vrow + (size_t)(rb + lr8) * NSEQ + jn + (lc8 ^ lr8) * 8,
                        &KVs[g][p ^ 1][1][rb * 64]);
        }

        const ushort* Ks = &KVs[g][p][0][0];
        const ushort* Vs = &KVs[g][p][1][0];

        // ---- S^T = K · Q^T : C-layout row j=quad*4+reg, col i=l15 ----
        f32x4 ST[2][4];
        #pragma unroll
        for (int jt = 0; jt < 4; ++jt) {
            bf16x8 kf0 = *(const bf16x8*)&Ks[(jt * 16 + l15) * 64 + ((0 + quad) ^ sw) * 8];
            bf16x8 kf1 = *(const bf16x8*)&Ks[(jt * 16 + l15) * 64 + ((4 + quad) ^ sw) * 8];
            #pragma unroll
            for (int mt = 0; mt < 2; ++mt) {
                ST[mt][jt] = __builtin_amdgcn_mfma_f32_16x16x32_bf16(kf0, qf[mt][0], z4, 0, 0, 0);
                ST[mt][jt] = __builtin_amdgcn_mfma_f32_16x16x32_bf16(kf1, qf[mt][1], ST[mt][jt], 0, 0, 0);
            }
        }

        // ---- no-max softmax: P = exp2(S); pack straight into PV B-frags ----
        s16x4 pb[2][4];
        #pragma unroll
        for (int mt = 0; mt < 2; ++mt) {
            #pragma unroll
            for (int jt = 0; jt < 4; ++jt) {
                float p0 = fexp2(ST[mt][jt][0]);
                float p1 = fexp2(ST[mt][jt][1]);
                float p2 = fexp2(ST[mt][jt][2]);
                float p3 = fexp2(ST[mt][jt][3]);
                lacc[mt] += (p0 + p1) + (p2 + p3);
                pb[mt][jt] = pk_bf4(p0, p1, p2, p3);
            }
        }

        // ---- O^T += V^T · P^T : V via b128 broadcast + cndmask half-select ----
        #pragma unroll
        for (int jt = 0; jt < 4; ++jt) {
            #pragma unroll
            for (int dt = 0; dt < 4; ++dt) {
                bf16x8 v8 = *(const bf16x8*)
                    &Vs[(dt * 16 + l15) * 64 + ((2 * jt + (quad >> 1)) ^ sw) * 8];
                uint4 u4 = __builtin_bit_cast(uint4, v8);
                uint s0 = (quad & 1) ? u4.z : u4.x;
                uint s1 = (quad & 1) ? u4.w : u4.y;
                s16x4 vf = __builtin_bit_cast(s16x4, make_uint2(s0, s1));
                Oacc[dt][0] = __builtin_amdgcn_mfma_f32_16x16x16bf16_1k(vf, pb[0][jt], Oacc[dt][0], 0, 0, 0);
                Oacc[dt][1] = __builtin_amdgcn_mfma_f32_16x16x16bf16_1k(vf, pb[1][jt], Oacc[dt][1], 0, 0, 0);
            }
        }

        __syncthreads();
    }

    #pragma unroll
    for (int mt = 0; mt < 2; ++mt) {
        lacc[mt] += __shfl_xor(lacc[mt], 16, 64);
        lacc[mt] += __shfl_xor(lacc[mt], 32, 64);
    }

    // ---- merge groups via LDS (overlay on KVs) ----
    float* M  = (float*)KVs;
    float* Lm = M + 4 * 64 * 36;
    const int slot = (ww * 64 + lane) * 36;
    if (g == 1) {
        #pragma unroll
        for (int dt = 0; dt < 4; ++dt)
            #pragma unroll
            for (int mt = 0; mt < 2; ++mt)
                *(f32x4*)&M[slot + (dt * 2 + mt) * 4] = Oacc[dt][mt];
        Lm[(ww * 64 + lane) * 2 + 0] = lacc[0];
        Lm[(ww * 64 + lane) * 2 + 1] = lacc[1];
    }
    __syncthreads();
    if (g == 0) {
        float ri[2];
        #pragma unroll
        for (int mt = 0; mt < 2; ++mt)
            ri[mt] = 1.f / (lacc[mt] + Lm[(ww * 64 + lane) * 2 + mt]);
        #pragma unroll
        for (int mt = 0; mt < 2; ++mt) {
            ushort* orow = attnb + ((size_t)b * NSEQ + i0 + ww * 32 + mt * 16 + l15) * 512 + h * 64;
            #pragma unroll
            for (int dt = 0; dt < 4; ++dt) {
                f32x4 o2 = *(const f32x4*)&M[slot + (dt * 2 + mt) * 4];
                *(ushort4*)&orow[dt * 16 + quad * 4] =
                    pk_bf4u((Oacc[dt][mt][0] + o2[0]) * ri[mt],
                            (Oacc[dt][mt][1] + o2[1]) * ri[mt],
                            (Oacc[dt][mt][2] + o2[2]) * ri[mt],
                            (Oacc[dt][mt][3] + o2[3]) * ri[mt]);
            }
        }
    }
}

// ---- GEMM2 (R9 version): out = w_out @ attn + bias. 64x64 tiles, BK=64, K=512. ----
__global__ __launch_bounds__(256)
void gemm_out(const ushort* __restrict__ A, const ushort* __restrict__ X,
              const float* __restrict__ bias, float* __restrict__ Y)
{
    const int K = 512;
    const int tid = threadIdx.x;
    const int w = tid >> 6, l15 = tid & 15, quad = (tid & 63) >> 4;
    const int n0 = blockIdx.x * 64, o0 = blockIdx.y * 64, b = blockIdx.z;

    __shared__ __align__(16) ushort As[64][72];
    __shared__ __align__(16) ushort Bs[64][72];

    f32x4 acc[4];
    const f32x4 z4 = {0.f, 0.f, 0.f, 0.f};
    #pragma unroll
    for (int nt = 0; nt < 4; ++nt) acc[nt] = z4;

    for (int k0 = 0; k0 < K; k0 += 64) {
        __syncthreads();
        #pragma unroll
        for (int c = 0; c < 2; ++c) {
            const int flat = c * 256 + tid;     // 0..511
            const int m = flat >> 3, ck = (flat & 7) * 8;
            *(uint4*)&As[m][ck] = *(const uint4*)&A[(size_t)(o0 + m) * K + k0 + ck];
            *(uint4*)&Bs[m][ck] =
                *(const uint4*)&X[((size_t)b * NSEQ + n0 + m) * K + k0 + ck];
        }
        __syncthreads();
        #pragma unroll
        for (int kk = 0; kk < 2; ++kk) {
            bf16x8 a0 = *(const bf16x8*)&As[w * 16 + l15][kk * 32 + quad * 8];
            #pragma unroll
            for (int nt = 0; nt < 4; ++nt) {
                bf16x8 bb = *(const bf16x8*)&Bs[nt * 16 + l15][kk * 32 + quad * 8];
                acc[nt] = __builtin_amdgcn_mfma_f32_16x16x32_bf16(a0, bb, acc[nt], 0, 0, 0);
            }
        }
    }

    float* Yb = Y + (size_t)b * 256 * NSEQ;
    #pragma unroll
    for (int reg = 0; reg < 4; ++reg) {
        const int o = o0 + w * 16 + quad * 4 + reg;
        const float bi = bias[o];
        #pragma unroll
        for (int nt = 0; nt < 4; ++nt)
            Yb[(size_t)o * NSEQ + n0 + nt * 16 + l15] = acc[nt][reg] + bi;
    }
}

extern "C" void kernel_launch(void* const* d_in, const int* in_sizes, int n_in,
                              void* d_out, int out_size, void* d_ws, size_t ws_size,
                              hipStream_t stream)
{
    const float* x     = (const float*)d_in[0];
    const float* w_qkv = (const float*)d_in[1];
    const float* w_out = (const float*)d_in[2];
    const float* b_out = (const float*)d_in[3];
    float* out = (float*)d_out;

    ushort* xb    = (ushort*)d_ws;                 // 2,097,152  [b][n][256]
    ushort* wqb   = xb    + 2097152;               //   393,216
    ushort* wob   = wqb   + 393216;                //   131,072
    ushort* Qt    = wob   + 131072;                // 4,194,304  [bh][n][64]
    ushort* Kt    = Qt    + 4194304;               // 4,194,304  [bh][n][64]
    ushort* vb    = Kt    + 4194304;               // 4,194,304  [b][512][n]
    ushort* attnb = vb    + 4194304;               // 4,194,304  [b][n][512]

    cvt_all<<<1024, 256, 0, stream>>>(x, w_qkv, w_out, xb, wqb, wob);

    gemm_qkv<<<dim3(16, 12, BATCH), 256, 0, stream>>>(wqb, xb, Qt, Kt, vb);

    attn8<<<dim3(16, 8, BATCH), 512, 0, stream>>>(Qt, Kt, vb, attnb);

    gemm_out<<<dim3(32, 4, BATCH), 256, 0, stream>>>(wob, attnb, b_out, out);
}